// Round 5
// baseline (1308.562 us; speedup 1.0000x reference)
//
#include <hip/hip_runtime.h>

#define BB 256
#define LL 1024
#define TT 128
#define NTH 1024   // 16 waves = 4 waves/SIMD (max for 1 resident block)
#define NG 8       // pred groups
#define PG 16      // preds per group
#define PVS 132    // padded stride for pv/pi (132 % 32 = 4 -> conflict-free merge reads)

// LDS-only barrier: does NOT drain vmcnt, so in-flight global prefetch loads
// stay outstanding across the barrier (__syncthreads drains vmcnt(0) too).
__device__ __forceinline__ void lds_barrier() {
    asm volatile("s_waitcnt lgkmcnt(0)\n\ts_barrier" ::);
}

struct SmallSmem {
    float state[TT];          // current Viterbi state (float4-aligned, first)
    float pv[NG * PVS];       // pv[g*PVS + j]: group-g partial best value for col j
    int   pi[NG * PVS];       // pi[g*PVS + j]: matching GLOBAL pred index
    unsigned char tags[LL];   // decoded tags staging
};

__global__ __launch_bounds__(NTH)
void viterbi_kernel(const float* __restrict__ x,
                    const int* __restrict__ lengths,
                    const float* __restrict__ trans,
                    int* __restrict__ out) {
    __shared__ SmallSmem sm;
    extern __shared__ unsigned char bp[];   // LL*TT bytes, backpointers in LDS

    const int b   = blockIdx.x;
    const int tid = threadIdx.x;
    // phase-1 assignment: column j, pred group g (preds [16g, 16g+16))
    const int j   = tid & (TT - 1);
    const int g   = tid >> 7;
    // phase-2 (merge) assignment: column jm, partial wm
    const int jm  = tid >> 3;
    const int wm  = tid & 7;

    int lenb = lengths[b];
    if (lenb < 1) lenb = 1;
    if (lenb > LL) lenb = LL;

    // Register-cache trans for this thread's 16 preds: tc[ii] = trans[16g+ii][j]
    float tc[PG];
    #pragma unroll
    for (int ii = 0; ii < PG; ++ii)
        tc[ii] = trans[(g * PG + ii) * TT + j];

    const float* xb = x + (size_t)b * LL * TT;

    if (tid < TT) sm.state[tid] = xb[tid];

    // Emission prefetch for the merge phase (thread owns column jm there).
    float xv_cur = 0.0f, xv_next = 0.0f;
    if (lenb > 1) xv_cur = xb[TT + jm];
    lds_barrier();

    // ---------------- forward ----------------
    for (int t = 1; t < lenb; ++t) {
        {   // prefetch next emission (floats across lgkm-only barriers)
            int tn = (t + 1 < lenb) ? (t + 1) : (lenb - 1);
            xv_next = xb[tn * TT + jm];
        }

        // Phase 1: 16 preds for column j. Residue accumulator r tracks local
        // ii = 4k+r, k ascending; strict > keeps the LOWEST index per residue
        // (jnp.argmax = first max).
        float a0 = -3.4e38f, a1 = -3.4e38f, a2 = -3.4e38f, a3 = -3.4e38f;
        int   i0 = 0, i1 = 1, i2 = 2, i3 = 3;
        const float4* st4 = reinterpret_cast<const float4*>(sm.state + g * PG);
        #pragma unroll
        for (int k = 0; k < 4; ++k) {
            float4 sv = st4[k];            // wave-uniform broadcast ds_read_b128
            float s0 = sv.x + tc[4 * k + 0];
            float s1 = sv.y + tc[4 * k + 1];
            float s2 = sv.z + tc[4 * k + 2];
            float s3 = sv.w + tc[4 * k + 3];
            if (s0 > a0) { a0 = s0; i0 = 4 * k + 0; }
            if (s1 > a1) { a1 = s1; i1 = 4 * k + 1; }
            if (s2 > a2) { a2 = s2; i2 = 4 * k + 2; }
            if (s3 > a3) { a3 = s3; i3 = 4 * k + 3; }
        }
        // merge residues with EXACT first-index tie-break (local ii order)
        float av = a0; int ax = i0;
        if (a1 > av || (a1 == av && i1 < ax)) { av = a1; ax = i1; }
        if (a2 > av || (a2 == av && i2 < ax)) { av = a2; ax = i2; }
        if (a3 > av || (a3 == av && i3 < ax)) { av = a3; ax = i3; }
        sm.pv[g * PVS + j] = av;
        sm.pi[g * PVS + j] = ax + g * PG;   // global predecessor index
        lds_barrier();

        // Phase 2 (ALL waves): 8-lane butterfly merge of the group partials.
        // Operator = lexicographic (max value, min index): associative and
        // commutative, so the xor-butterfly yields exact first-max semantics.
        float mv = sm.pv[wm * PVS + jm];
        int   mi = sm.pi[wm * PVS + jm];
        #pragma unroll
        for (int m = 1; m <= 4; m <<= 1) {
            float ov = __shfl_xor(mv, m, 64);
            int   oi = __shfl_xor(mi, m, 64);
            if (ov > mv || (ov == mv && oi < mi)) { mv = ov; mi = oi; }
        }
        if (wm == 0) {
            sm.state[jm] = mv + xv_cur;
            bp[t * TT + jm] = (unsigned char)mi;
        }
        xv_cur = xv_next;
        lds_barrier();
    }

    // ---------------- backward ----------------
    if (tid == 0) {
        // last_tag = argmax(state), first-index tiebreak (sequential strict >)
        float bv = sm.state[0]; int ix = 0;
        for (int i = 1; i < TT; ++i) {
            float v = sm.state[i];
            if (v > bv) { bv = v; ix = i; }
        }
        int carry = ix;
        for (int t = lenb - 1; t >= 1; --t) {
            sm.tags[t] = (unsigned char)carry;
            carry = bp[t * TT + carry];
        }
        sm.tags[0] = (unsigned char)carry;
    }
    lds_barrier();

    int* outb = out + (size_t)b * LL;
    for (int t = tid; t < LL; t += NTH)
        outb[t] = (t < lenb) ? (int)sm.tags[t] : 0;
}

extern "C" void kernel_launch(void* const* d_in, const int* in_sizes, int n_in,
                              void* d_out, int out_size, void* d_ws, size_t ws_size,
                              hipStream_t stream) {
    const float* x       = (const float*)d_in[0];
    const int*   lengths = (const int*)d_in[1];
    // d_in[2] = tags (unused by decode)
    const float* trans   = (const float*)d_in[3];
    int*         out     = (int*)d_out;

    // Backpointers entirely in LDS: 128 KB dynamic + ~10 KB static < 160 KB.
    const int dyn = LL * TT;  // 131072 bytes
    hipFuncSetAttribute((const void*)&viterbi_kernel,
                        hipFuncAttributeMaxDynamicSharedMemorySize, dyn);
    viterbi_kernel<<<BB, NTH, dyn, stream>>>(x, lengths, trans, out);
}

// Round 6
// 1028.936 us; speedup vs baseline: 1.2718x; 1.2718x over previous
//
#include <hip/hip_runtime.h>

#define BB 256
#define LL 1024
#define TT 128
#define NTH 512    // 8 waves = 2 waves/SIMD (best measured config)
#define CPW 16     // columns per wave
#define SCP 132    // per-copy stride in floats (132 mod 32 = 4 -> staggered banks)
#define SB  (4 * SCP)  // one state buffer: 4 padded copies = 528 floats

// LDS-only barrier: does NOT drain vmcnt, so in-flight global prefetch loads
// stay outstanding across the barrier (__syncthreads drains vmcnt(0) too).
__device__ __forceinline__ void lds_barrier() {
    asm volatile("s_waitcnt lgkmcnt(0)\n\ts_barrier" ::);
}

struct SmallSmem {
    // Double-buffered state, each buffer = 4 bank-staggered copies (copy g is
    // read by the g-quarter lanes: float offset 164g+4k hits banks 4(g+k)..+3,
    // disjoint across g -> conflict-free broadcast reads).
    float scopy[2 * SB];      // 4224 B, 16B-aligned (first member)
    unsigned char tags[LL];   // decoded tags staging
};

__global__ __launch_bounds__(NTH)
void viterbi_kernel(const float* __restrict__ x,
                    const int* __restrict__ lengths,
                    const float* __restrict__ trans,
                    int* __restrict__ out) {
    __shared__ SmallSmem sm;
    extern __shared__ unsigned char bp[];   // LL*TT bytes, backpointers in LDS

    const int b    = blockIdx.x;
    const int tid  = threadIdx.x;
    const int lane = tid & 63;
    const int w    = tid >> 6;        // wave 0..7 owns columns [16w, 16w+16)
    const int c    = lane & 15;       // column slot within wave
    const int g    = lane >> 4;       // pred quarter: preds [32g, 32g+32)
    const int j    = w * CPW + c;     // this thread's column

    int lenb = lengths[b];
    if (lenb < 1) lenb = 1;
    if (lenb > LL) lenb = LL;

    // Register-cache trans for this thread's 32 preds: tc[ii] = trans[32g+ii][j]
    float tc[32];
    #pragma unroll
    for (int ii = 0; ii < 32; ++ii)
        tc[ii] = trans[(g * 32 + ii) * TT + j];

    const float* xb = x + (size_t)b * LL * TT;

    // Init: state(t=0) = x[0]; first read (t=1) uses buffer (1&1)=1.
    if (tid < TT) {
        float v = xb[tid];
        #pragma unroll
        for (int gg = 0; gg < 4; ++gg)
            sm.scopy[SB + gg * SCP + tid] = v;
    }

    // Emission prefetch for this thread's column.
    float xv_cur = 0.0f, xv_next = 0.0f;
    if (lenb > 1) xv_cur = xb[TT + j];
    lds_barrier();

    // ---------------- forward (ONE barrier per step) ----------------
    for (int t = 1; t < lenb; ++t) {
        {   // prefetch next emission (vmcnt load floats across lgkm-only barrier)
            int tn = (t + 1 < lenb) ? (t + 1) : (lenb - 1);
            xv_next = xb[tn * TT + j];
        }

        // Scan 32 preds from this quarter's padded copy (conflict-free b128
        // broadcast: 16 c-lanes share each address). Residue accumulator r
        // tracks local ii = 4k+r, k ascending; strict > keeps the LOWEST index
        // within each residue (jnp.argmax = first max).
        const float4* st4 = reinterpret_cast<const float4*>(
            sm.scopy + (t & 1) * SB + 164 * g);   // g*SCP + 32g = 164g
        float a0 = -3.4e38f, a1 = -3.4e38f, a2 = -3.4e38f, a3 = -3.4e38f;
        int   i0 = 0, i1 = 1, i2 = 2, i3 = 3;
        #pragma unroll
        for (int k = 0; k < 8; ++k) {
            float4 sv = st4[k];
            float s0 = sv.x + tc[4 * k + 0];
            float s1 = sv.y + tc[4 * k + 1];
            float s2 = sv.z + tc[4 * k + 2];
            float s3 = sv.w + tc[4 * k + 3];
            if (s0 > a0) { a0 = s0; i0 = 4 * k + 0; }
            if (s1 > a1) { a1 = s1; i1 = 4 * k + 1; }
            if (s2 > a2) { a2 = s2; i2 = 4 * k + 2; }
            if (s3 > a3) { a3 = s3; i3 = 4 * k + 3; }
        }
        // Merge residues with EXACT first-index tie-break (local index order).
        float av = a0; int ax = i0;
        if (a1 > av || (a1 == av && i1 < ax)) { av = a1; ax = i1; }
        if (a2 > av || (a2 == av && i2 < ax)) { av = a2; ax = i2; }
        if (a3 > av || (a3 == av && i3 < ax)) { av = a3; ax = i3; }

        // In-wave butterfly across the 4 pred-quarters (lane bits 4,5 = g).
        // Operator = lexicographic (max value, min GLOBAL index): associative
        // and commutative -> exact first-max over all 128 preds.
        float mv = av; int mi = g * 32 + ax;
        #pragma unroll
        for (int m = 16; m <= 32; m <<= 1) {
            float ov = __shfl_xor(mv, m, 64);
            int   oi = __shfl_xor(mi, m, 64);
            if (ov > mv || (ov == mv && oi < mi)) { mv = ov; mi = oi; }
        }

        // All 4 g-lanes of column j hold identical (mv, mi): each writes its
        // own padded copy in the OTHER buffer (double-buffer -> no WAR race,
        // single barrier suffices).
        sm.scopy[((t + 1) & 1) * SB + g * SCP + j] = mv + xv_cur;
        if (g == 0) bp[t * TT + j] = (unsigned char)mi;
        xv_cur = xv_next;
        lds_barrier();
    }

    // ---------------- backward ----------------
    if (tid == 0) {
        const float* fin = sm.scopy + (lenb & 1) * SB;  // copy g=0 of final state
        float bv = fin[0]; int ix = 0;
        for (int i = 1; i < TT; ++i) {
            float v = fin[i];
            if (v > bv) { bv = v; ix = i; }   // first-index tiebreak
        }
        int carry = ix;
        for (int t = lenb - 1; t >= 1; --t) {
            sm.tags[t] = (unsigned char)carry;
            carry = bp[t * TT + carry];
        }
        sm.tags[0] = (unsigned char)carry;
    }
    lds_barrier();

    int* outb = out + (size_t)b * LL;
    for (int t = tid; t < LL; t += NTH)
        outb[t] = (t < lenb) ? (int)sm.tags[t] : 0;
}

extern "C" void kernel_launch(void* const* d_in, const int* in_sizes, int n_in,
                              void* d_out, int out_size, void* d_ws, size_t ws_size,
                              hipStream_t stream) {
    const float* x       = (const float*)d_in[0];
    const int*   lengths = (const int*)d_in[1];
    // d_in[2] = tags (unused by decode)
    const float* trans   = (const float*)d_in[3];
    int*         out     = (int*)d_out;

    // Backpointers entirely in LDS: 128 KB dynamic + ~5.5 KB static < 160 KB.
    const int dyn = LL * TT;  // 131072 bytes
    hipFuncSetAttribute((const void*)&viterbi_kernel,
                        hipFuncAttributeMaxDynamicSharedMemorySize, dyn);
    viterbi_kernel<<<BB, NTH, dyn, stream>>>(x, lengths, trans, out);
}